// Round 7
// baseline (571.578 us; speedup 1.0000x reference)
//
#include <hip/hip_runtime.h>
#include <stdint.h>

#define NTAGS 256
#define BATCH 64
#define SEQ   512
#define NTHREADS 1024   // 16 waves: thread (q=tid>>8, k=tid&255); q = quarter of j-range

#if __has_builtin(__builtin_amdgcn_fdot2_f32_bf16)
#define HAVE_DOT2_BF16 1
typedef __bf16 bf16x2_t __attribute__((ext_vector_type(2)));
#define BCAST(x) __builtin_bit_cast(bf16x2_t, (unsigned int)(x))
#endif

// ---------------- wave (64-lane) reductions ----------------
__device__ __forceinline__ float wave_max(float v) {
#pragma unroll
  for (int o = 32; o; o >>= 1) v = fmaxf(v, __shfl_xor(v, o));
  return v;
}
__device__ __forceinline__ float wave_sum(float v) {
#pragma unroll
  for (int o = 32; o; o >>= 1) v += __shfl_xor(v, o);
  return v;
}

// f32 -> bf16 bits, round-to-nearest-even
__device__ __forceinline__ unsigned int f32_to_bf16_bits(float f) {
  unsigned int u = __float_as_uint(f);
  return (u + 0x7FFFu + ((u >> 16) & 1u)) >> 16;
}
__device__ __forceinline__ unsigned int pack_bf16x2(float lo, float hi) {
  return (f32_to_bf16_bits(lo) & 0xFFFFu) | (f32_to_bf16_bits(hi) << 16);
}

// 32 packed-bf16x2 ET words per thread (proven resident: VGPR_Count=60 in r6).
#define ET32(M) \
  M(0) M(1) M(2) M(3) M(4) M(5) M(6) M(7) \
  M(8) M(9) M(10) M(11) M(12) M(13) M(14) M(15) \
  M(16) M(17) M(18) M(19) M(20) M(21) M(22) M(23) \
  M(24) M(25) M(26) M(27) M(28) M(29) M(30) M(31)

#define ET_DECL(p) unsigned int et##p;
#define ET_INIT(p) \
  et##p = f32_to_bf16_bits(exp2f(trans[(64*q + 2*(p))      * NTAGS + k] * LOG2E)) | \
          (f32_to_bf16_bits(exp2f(trans[(64*q + 2*(p) + 1) * NTAGS + k] * LOG2E)) << 16);

// accumulator chain per step index: p % 4 (direct literal paste)
#define ACC(p) ACC_##p
#define ACC_0  acc0
#define ACC_1  acc1
#define ACC_2  acc2
#define ACC_3  acc3
#define ACC_4  acc0
#define ACC_5  acc1
#define ACC_6  acc2
#define ACC_7  acc3
#define ACC_8  acc0
#define ACC_9  acc1
#define ACC_10 acc2
#define ACC_11 acc3
#define ACC_12 acc0
#define ACC_13 acc1
#define ACC_14 acc2
#define ACC_15 acc3
#define ACC_16 acc0
#define ACC_17 acc1
#define ACC_18 acc2
#define ACC_19 acc3
#define ACC_20 acc0
#define ACC_21 acc1
#define ACC_22 acc2
#define ACC_23 acc3
#define ACC_24 acc0
#define ACC_25 acc1
#define ACC_26 acc2
#define ACC_27 acc3
#define ACC_28 acc0
#define ACC_29 acc1
#define ACC_30 acc2
#define ACC_31 acc3

#if HAVE_DOT2_BF16
#define DOT_STEP(p) { \
    int s_ = __builtin_amdgcn_readlane(w0, p); \
    ACC(p) = __builtin_amdgcn_fdot2_f32_bf16(BCAST(et##p), BCAST(s_), ACC(p), false); }
#else
#define DOT_STEP(p) { \
    unsigned int s_ = (unsigned int)__builtin_amdgcn_readlane(w0, p); \
    ACC(p) = fmaf(__uint_as_float(s_ << 16),         __uint_as_float(et##p << 16),         ACC(p)); \
    ACC(p) = fmaf(__uint_as_float(s_ & 0xFFFF0000u), __uint_as_float(et##p & 0xFFFF0000u), ACC(p)); }
#endif

// One block (16 waves) per batch element. Linear-domain forward recursion.
// SINGLE barrier per step (r6 had 2 + a 4-wave-only epilogue on the critical
// path): every thread computes partial for tag k AND rebuilds its own alpha
// pair (j0 = 64q+2*(lane&31), j0+1) from the quarter partials after the
// barrier. Renorm is deferred one step and fused into exp2(g*log2e - e).
__global__ __launch_bounds__(NTHREADS, 4)
void crf_fwd(const float* __restrict__ logits,
             const int*   __restrict__ tags,
             const int*   __restrict__ mask,
             const float* __restrict__ trans,
             float* __restrict__ out)
{
  const int b    = blockIdx.x;
  const int tid  = threadIdx.x;
  const int k    = tid & 255;
  const int q    = tid >> 8;        // wave-uniform
  const int lane = tid & 63;
  const int wid  = tid >> 6;        // 0..15
  const int L    = lane & 31;
  const int j0   = (q << 6) + (L << 1);   // this thread's alpha-pair index

  __shared__ float part[2][4][NTAGS];  // [buf][quarter][tag] partials, double-buffered
  __shared__ float maxw[16];
  __shared__ float redf[4];
  __shared__ float rnum[16], rms[16];

  const float LOG2E = 1.4426950408889634f;
  const float LN2   = 0.6931471805599453f;

  const float* lg = logits + (size_t)b * SEQ * NTAGS;
  const int*   tg = tags + b * SEQ;
  const int*   mk = mask + b * SEQ;

  // ---------------- numerator (joint likelihood) ----------------
  float numer = 0.f, msum = 0.f;
  for (int t = tid; t < SEQ; t += NTHREADS) {
    int   tag_t = tg[t];
    float m_t   = (float)mk[t];
    msum += m_t;
    if (t < SEQ - 1) {
      numer += lg[t * NTAGS + tag_t] * m_t;                       // emit, mask[:, :-1]
      numer += trans[tag_t * NTAGS + tg[t + 1]] * (float)mk[t+1]; // trans, mask[:, 1:]
    }
  }
  numer = wave_sum(numer);
  msum  = wave_sum(msum);
  if (lane == 0) { rnum[wid] = numer; rms[wid] = msum; }
  __syncthreads();
  float numer_tot = 0.f, msum_tot = 0.f;
#pragma unroll
  for (int w = 0; w < 16; ++w) { numer_tot += rnum[w]; msum_tot += rms[w]; }
  __syncthreads();

  // ---------------- ET quarter-column -> 32 named registers ----------------
  ET32(ET_DECL)
  ET32(ET_INIT)

  // ---------------- init alpha pair at t=0 (no LDS needed) ----------------
  const float* lgj = lg + j0;
  float a0, a1;
  {
    const float2 gi = *(const float2*)lgj;     // logits[b,0,j0..j0+1]
    a0 = exp2f(gi.x * LOG2E);
    a1 = exp2f(gi.y * LOG2E);
  }
  unsigned int w0 = pack_bf16x2(a0, a1);
  int esum = 0;

  // prefetch logits pair + mask two steps ahead
  float2 gA = *(const float2*)(lgj + 1 * NTAGS);
  float2 gB = *(const float2*)(lgj + 2 * NTAGS);
  int mA = mk[1], mB = mk[2];

  int cur = 0;
#pragma unroll 2
  for (int t = 1; t < SEQ; ++t) {
    const float2 g = gA;  const int m = mA;
    gA = gB; mA = mB;
    const int tp = (t + 2 < SEQ) ? (t + 2) : (SEQ - 1);
    gB = *(const float2*)(lgj + tp * NTAGS);
    mB = mk[tp];

    // ---- dots: partial_{q,k} = sum_{j in Q_q} a_j * ET[j,k] ----
    float acc0 = 0.f, acc1 = 0.f, acc2 = 0.f, acc3 = 0.f;
    ET32(DOT_STEP)   // 32x { v_readlane -> SGPR ; v_dot2_f32_bf16 }
    part[cur][q][k] = (acc0 + acc1) + (acc2 + acc3);   // k=64*(wid&3)+lane: conflict-free
    __syncthreads();   // the ONLY barrier in the step

    // ---- rebuild own alpha pair from the 4 quarter partials ----
    const float2 P0 = *(const float2*)&part[cur][0][j0];  // lane-stride 8B: 2-way max
    const float2 P1 = *(const float2*)&part[cur][1][j0];
    const float2 P2 = *(const float2*)&part[cur][2][j0];
    const float2 P3 = *(const float2*)&part[cur][3][j0];
    const float sum0 = (P0.x + P1.x) + (P2.x + P3.x);
    const float sum1 = (P0.y + P1.y) + (P2.y + P3.y);

    int e = 0;
    if ((t & 3) == 0) {   // apply renorm computed at t-1 (first at t=4)
      const float4 x0 = *(const float4*)&maxw[0];
      const float4 x1 = *(const float4*)&maxw[4];
      const float4 x2 = *(const float4*)&maxw[8];
      const float4 x3 = *(const float4*)&maxw[12];
      float mx = fmaxf(fmaxf(fmaxf(x0.x, x0.y), fmaxf(x0.z, x0.w)),
                       fmaxf(fmaxf(x1.x, x1.y), fmaxf(x1.z, x1.w)));
      mx = fmaxf(mx, fmaxf(fmaxf(fmaxf(x2.x, x2.y), fmaxf(x2.z, x2.w)),
                           fmaxf(fmaxf(x3.x, x3.y), fmaxf(x3.z, x3.w))));
      e = (int)((__float_as_uint(mx) >> 23) & 0xFF) - 127;
      esum += e;
    }
    const float fe  = (float)e;
    const float na0 = sum0 * exp2f(fmaf(g.x, LOG2E, -fe));   // renorm fused, exact pow2
    const float na1 = sum1 * exp2f(fmaf(g.y, LOG2E, -fe));
    const float sc  = __uint_as_float((unsigned int)(127 - e) << 23);  // 2^-e
    a0 = m ? na0 : a0 * sc;   // mask: freeze alpha (still scale for consistency)
    a1 = m ? na1 : a1 * sc;

    if ((t & 3) == 3) {   // compute renorm max, applied at t+1 (no extra barrier)
      const float mx2 = wave_max(fmaxf(a0, a1));
      if (lane == 0) maxw[wid] = mx2;
    }
    w0 = pack_bf16x2(a0, a1);
    cur ^= 1;
  }

  // ---------------- log_den = log(sum_j a) + esum*ln2 ----------------
  // representatives: first wave of each q-group, lanes 0..31 (each holds 2 j's)
  float v = (((wid & 3) == 0) && lane < 32) ? (a0 + a1) : 0.f;
  v = wave_sum(v);
  if (lane == 0 && (wid & 3) == 0) redf[wid >> 2] = v;
  __syncthreads();

  if (tid == 0) {
    const float ssum = (redf[0] + redf[1]) + (redf[2] + redf[3]);
    const float log_den = logf(ssum) + (float)esum * LN2;
    int last_idx = (int)msum_tot - 1;
    if (last_idx < 0) last_idx = 0;
    const int last_tag = tg[last_idx];
    const float score = numer_tot + lg[(SEQ - 1) * NTAGS + last_tag] * (float)mk[SEQ - 1];
    atomicAdd(out, score - log_den);
  }
}

extern "C" void kernel_launch(void* const* d_in, const int* in_sizes, int n_in,
                              void* d_out, int out_size, void* d_ws, size_t ws_size,
                              hipStream_t stream) {
  const float* logits = (const float*)d_in[0];
  const int*   tags   = (const int*)d_in[1];
  const int*   mask   = (const int*)d_in[2];
  const float* trans  = (const float*)d_in[3];
  float* out = (float*)d_out;

  hipMemsetAsync(out, 0, sizeof(float), stream);  // harness poisons d_out with 0xAA
  crf_fwd<<<dim3(BATCH), dim3(NTHREADS), 0, stream>>>(logits, tags, mask, trans, out);
}

// Round 8
// 472.192 us; speedup vs baseline: 1.2105x; 1.2105x over previous
//
#include <hip/hip_runtime.h>
#include <stdint.h>

#define NTAGS 256
#define BATCH 64
#define SEQ   512
#define NTHREADS 1024   // 16 waves: thread (q=tid>>8, k=tid&255)

#if __has_builtin(__builtin_amdgcn_fdot2_f32_bf16)
#define HAVE_DOT2_BF16 1
typedef __bf16 bf16x2_t __attribute__((ext_vector_type(2)));
#define BCAST(x) __builtin_bit_cast(bf16x2_t, (unsigned int)(x))
#endif

__device__ __forceinline__ float wave_max(float v) {
#pragma unroll
  for (int o = 32; o; o >>= 1) v = fmaxf(v, __shfl_xor(v, o));
  return v;
}
__device__ __forceinline__ float wave_sum(float v) {
#pragma unroll
  for (int o = 32; o; o >>= 1) v += __shfl_xor(v, o);
  return v;
}

__device__ __forceinline__ unsigned int f32_to_bf16_bits(float f) {
  unsigned int u = __float_as_uint(f);
  return (u + 0x7FFFu + ((u >> 16) & 1u)) >> 16;
}

// 32 packed-bf16x2 ET words per thread (proven resident: VGPR=60 in r6)
#define ET32(M) \
  M(0) M(1) M(2) M(3) M(4) M(5) M(6) M(7) \
  M(8) M(9) M(10) M(11) M(12) M(13) M(14) M(15) \
  M(16) M(17) M(18) M(19) M(20) M(21) M(22) M(23) \
  M(24) M(25) M(26) M(27) M(28) M(29) M(30) M(31)

#define ET_DECL(p) unsigned int et##p;
#define ET_INIT(p) \
  et##p = f32_to_bf16_bits(exp2f(trans[(64*q + 2*(p))      * NTAGS + k] * LOG2E)) | \
          (f32_to_bf16_bits(exp2f(trans[(64*q + 2*(p) + 1) * NTAGS + k] * LOG2E)) << 16);

// accumulator chain = p % 4 (literal paste)
#define ACC(p) ACC_##p
#define ACC_0  acc0
#define ACC_1  acc1
#define ACC_2  acc2
#define ACC_3  acc3
#define ACC_4  acc0
#define ACC_5  acc1
#define ACC_6  acc2
#define ACC_7  acc3
#define ACC_8  acc0
#define ACC_9  acc1
#define ACC_10 acc2
#define ACC_11 acc3
#define ACC_12 acc0
#define ACC_13 acc1
#define ACC_14 acc2
#define ACC_15 acc3
#define ACC_16 acc0
#define ACC_17 acc1
#define ACC_18 acc2
#define ACC_19 acc3
#define ACC_20 acc0
#define ACC_21 acc1
#define ACC_22 acc2
#define ACC_23 acc3
#define ACC_24 acc0
#define ACC_25 acc1
#define ACC_26 acc2
#define ACC_27 acc3
#define ACC_28 acc0
#define ACC_29 acc1
#define ACC_30 acc2
#define ACC_31 acc3

// hoisted readlanes: 8 independent readlanes, THEN 8 dots consuming SGPRs
// >=8 instructions old (kills the readlane->dot2 wait-state hazard of r6)
#define RL1(p)  const int srg##p = __builtin_amdgcn_readlane((int)w0v, p);
#if HAVE_DOT2_BF16
#define DT1(p)  ACC(p) = __builtin_amdgcn_fdot2_f32_bf16(BCAST(et##p), BCAST(srg##p), ACC(p), false);
#else
#define DT1(p)  { unsigned int u_ = (unsigned int)srg##p; \
  ACC(p) = fmaf(__uint_as_float(u_ << 16),         __uint_as_float(et##p << 16),         ACC(p)); \
  ACC(p) = fmaf(__uint_as_float(u_ & 0xFFFF0000u), __uint_as_float(et##p & 0xFFFF0000u), ACC(p)); }
#endif
#define GRP8(a,b,c,d,e0,f0,g0,h0) \
  RL1(a) RL1(b) RL1(c) RL1(d) RL1(e0) RL1(f0) RL1(g0) RL1(h0) \
  DT1(a) DT1(b) DT1(c) DT1(d) DT1(e0) DT1(f0) DT1(g0) DT1(h0)

// One forward step. APPLY/MEASURE are literal 0/1 (loop unrolled x4 so the
// renorm branches fold). Renorm: max measured at t%4==3 (before bar2, no
// extra barrier), applied at the next t%4==0 fused into exp2(g*log2e - e).
#define STEP(t, APPLY, MEASURE) { \
    const unsigned int w0v = abuf[(q << 5) + L32];  /* broadcast: 2 lanes/addr */ \
    float acc0 = 0.f, acc1 = 0.f, acc2 = 0.f, acc3 = 0.f; \
    GRP8(0,1,2,3,4,5,6,7) \
    GRP8(8,9,10,11,12,13,14,15) \
    GRP8(16,17,18,19,20,21,22,23) \
    GRP8(24,25,26,27,28,29,30,31) \
    part[q][k] = (acc0 + acc1) + (acc2 + acc3); \
    __syncthreads(); \
    if (tid < 256) { \
      const float g = gA;  const int m = mA; \
      gA = gB; mA = mB; \
      const int tp_ = ((t) + 2 < SEQ) ? ((t) + 2) : (SEQ - 1); \
      gB = lg[tp_ * NTAGS + k]; \
      mB = mk[tp_]; \
      const float s = (part[0][k] + part[1][k]) + (part[2][k] + part[3][k]); \
      int e = 0; \
      if (APPLY) { \
        const float4 mx4 = *(const float4*)maxw; \
        const float mx = fmaxf(fmaxf(mx4.x, mx4.y), fmaxf(mx4.z, mx4.w)); \
        e = (int)((__float_as_uint(mx) >> 23) & 0xFF) - 127; \
        esum += e; \
      } \
      const float cand = s * exp2f(fmaf(g, LOG2E, -(float)e)); \
      const float sc = APPLY ? __uint_as_float((unsigned int)(127 - e) << 23) : 1.0f; \
      mya = m ? cand : mya * sc; \
      if (MEASURE) { \
        const float mxv = wave_max(mya); \
        if (lane == 0) maxw[wid] = mxv; \
      } \
      ((unsigned short*)abuf)[k] = (unsigned short)f32_to_bf16_bits(mya); \
    } \
    __syncthreads(); }

__global__ __launch_bounds__(NTHREADS, 4)
void crf_fwd(const float* __restrict__ logits,
             const int*   __restrict__ tags,
             const int*   __restrict__ mask,
             const float* __restrict__ trans,
             float* __restrict__ out)
{
  const int b    = blockIdx.x;
  const int tid  = threadIdx.x;
  const int k    = tid & 255;
  const int q    = tid >> 8;        // wave-uniform quarter
  const int lane = tid & 63;
  const int wid  = tid >> 6;        // 0..15
  const int L32  = lane & 31;

  __shared__ unsigned int abuf[NTAGS / 2];   // alpha, packed bf16x2 (single buffer OK:
                                             // reads precede bar1, write is between bars)
  __shared__ float part[4][NTAGS];           // quarter partials
  __shared__ __align__(16) float maxw[4];    // renorm maxes (waves 0-3 of phase B)
  __shared__ float redf[4];
  __shared__ float rnum[16], rms[16];

  const float LOG2E = 1.4426950408889634f;
  const float LN2   = 0.6931471805599453f;

  const float* lg = logits + (size_t)b * SEQ * NTAGS;
  const int*   tg = tags + b * SEQ;
  const int*   mk = mask + b * SEQ;

  // ---------------- numerator (joint likelihood) ----------------
  float numer = 0.f, msum = 0.f;
  for (int t = tid; t < SEQ; t += NTHREADS) {
    int   tag_t = tg[t];
    float m_t   = (float)mk[t];
    msum += m_t;
    if (t < SEQ - 1) {
      numer += lg[t * NTAGS + tag_t] * m_t;
      numer += trans[tag_t * NTAGS + tg[t + 1]] * (float)mk[t + 1];
    }
  }
  numer = wave_sum(numer);
  msum  = wave_sum(msum);
  if (lane == 0) { rnum[wid] = numer; rms[wid] = msum; }
  __syncthreads();
  float numer_tot = 0.f, msum_tot = 0.f;
#pragma unroll
  for (int w = 0; w < 16; ++w) { numer_tot += rnum[w]; msum_tot += rms[w]; }
  __syncthreads();

  // ---------------- ET quarter-column -> 32 named registers ----------------
  ET32(ET_DECL)
  ET32(ET_INIT)

  // ---------------- init alpha at t=0 ----------------
  float mya = 0.f;
  int esum = 0;
  if (tid < 256) {
    mya = exp2f(lg[k] * LOG2E);
    ((unsigned short*)abuf)[k] = (unsigned short)f32_to_bf16_bits(mya);
  }
  __syncthreads();

  // prefetch logits/mask two steps ahead (phase-B threads only)
  float gA = 0.f, gB = 0.f;
  int   mA = 1,  mB = 1;
  if (tid < 256) {
    gA = lg[1 * NTAGS + k];
    gB = lg[2 * NTAGS + k];
    mA = mk[1];
    mB = mk[2];
  }

  // steps 1..3 (first renorm measure at t=3)
  STEP(1, 0, 0)
  STEP(2, 0, 0)
  STEP(3, 0, 1)

  // groups of 4: apply renorm at t==4g, measure at t==4g+3
#pragma unroll 1
  for (int tb = 4; tb < SEQ; tb += 4) {
    STEP(tb + 0, 1, 0)
    STEP(tb + 1, 0, 0)
    STEP(tb + 2, 0, 0)
    STEP(tb + 3, 0, 1)
  }

  // ---------------- log_den = log(sum_k a) + esum*ln2 ----------------
  if (tid < 256) {
    float ssum = wave_sum(mya);
    if (lane == 0) redf[wid] = ssum;
  }
  __syncthreads();

  if (tid == 0) {
    const float ssum = (redf[0] + redf[1]) + (redf[2] + redf[3]);
    const float log_den = logf(ssum) + (float)esum * LN2;
    int last_idx = (int)msum_tot - 1;
    if (last_idx < 0) last_idx = 0;
    const int last_tag = tg[last_idx];
    const float score = numer_tot + lg[(SEQ - 1) * NTAGS + last_tag] * (float)mk[SEQ - 1];
    atomicAdd(out, score - log_den);
  }
}

extern "C" void kernel_launch(void* const* d_in, const int* in_sizes, int n_in,
                              void* d_out, int out_size, void* d_ws, size_t ws_size,
                              hipStream_t stream) {
  const float* logits = (const float*)d_in[0];
  const int*   tags   = (const int*)d_in[1];
  const int*   mask   = (const int*)d_in[2];
  const float* trans  = (const float*)d_in[3];
  float* out = (float*)d_out;

  hipMemsetAsync(out, 0, sizeof(float), stream);  // harness poisons d_out
  crf_fwd<<<dim3(BATCH), dim3(NTHREADS), 0, stream>>>(logits, tags, mask, trans, out);
}